// Round 15
// baseline (6311.882 us; speedup 1.0000x reference)
//
#include <hip/hip_runtime.h>
#include <math.h>

#define NB 256   // batch
#define NT 512   // time steps
#define NF 65    // features
#define NH 512   // hidden
#define NCL 8    // clusters == physical XCDs
#define BPC 32   // blocks per cluster
#define BCL 32   // batch rows per cluster
#define XMS 136  // padded xm row stride (f16)
#define STPL (NCL*BCL*BPC*2)   // stats plane (one parity), floats

typedef __attribute__((ext_vector_type(8))) _Float16 f16x8;
typedef __attribute__((ext_vector_type(4))) float   f32x4;
typedef __attribute__((ext_vector_type(4))) unsigned u32x4;
typedef __attribute__((ext_vector_type(4))) int      i32x4;

// r14 schedule + per-wave asymmetric epoch barrier. Rings: h depth-4, stats parity-2.
__device__ __align__(16) int      g_claim[NCL];
__device__ __align__(16) int      g_wflag[NCL][2][64];         // [cl][lay][q*2+p] epoch flags
__device__ __align__(16) _Float16 g_h1[NCL*4*BCL*NH];          // [cl][slot][32][512]
__device__ __align__(16) _Float16 g_h2[NCL*4*BCL*NH];
__device__ __align__(16) float    g_stats[2][STPL];            // t-parity
__device__ __align__(16) float    g_pool[NB*NH];
__device__ __align__(16) float    g_Wt[NH*(NH/2)];
__device__ __align__(16) _Float16 g_xm[(size_t)NB*NT*XMS + 256];

__device__ __forceinline__ float sigm(float v)  { return 1.f/(1.f+__expf(-v)); }
__device__ __forceinline__ float tanh_(float v) { return 1.f-2.f/(1.f+__expf(2.f*v)); }

// COMPILER-MODELED coherent load (r12/r14-proven, spill-safe). cpol 17 = SC0|SC1.
__device__ u32x4 llvm_amdgcn_raw_buffer_load_i32x4(i32x4 srsrc, int voffset,
                                                   int soffset, int cpol)
    __asm("llvm.amdgcn.raw.buffer.load.v4i32");
__device__ __forceinline__ u32x4 bld(i32x4 srd, int vo) {
  return llvm_amdgcn_raw_buffer_load_i32x4(srd, vo, 0, 17);
}
__device__ __forceinline__ f16x8 bldh(i32x4 srd, int vo) {
  return __builtin_bit_cast(f16x8, bld(srd, vo));
}
__device__ __forceinline__ i32x4 make_srd(const void* base) {
  union { i32x4 v; unsigned u[4]; } s;
  s.u[0] = (unsigned)(unsigned long long)base;
  s.u[1] = (unsigned)(((unsigned long long)base) >> 32);  // stride = 0
  s.u[2] = 0xFFFFFFFFu;                                   // no bounds check
  s.u[3] = 0x00020000u;                                   // raw dword config
  return s.v;
}

// PROVEN store side (r4-r14): agent-scope relaxed atomic stores.
__device__ __forceinline__ void st_c(unsigned* p, unsigned v) {
  __hip_atomic_store(p, v, __ATOMIC_RELAXED, __HIP_MEMORY_SCOPE_AGENT);
}
__device__ __forceinline__ void st_c64(unsigned long long* p, unsigned long long v) {
  __hip_atomic_store(p, v, __ATOMIC_RELAXED, __HIP_MEMORY_SCOPE_AGENT);
}
__device__ __forceinline__ void st_fl(int* p, int v) {
  __hip_atomic_store(p, v, __ATOMIC_RELAXED, __HIP_MEMORY_SCOPE_AGENT);
}
__device__ __forceinline__ int ld_fl(const int* p) {
  return __hip_atomic_load((int*)p, __ATOMIC_RELAXED, __HIP_MEMORY_SCOPE_AGENT);
}

#define MF(a,b,c) __builtin_amdgcn_mfma_f32_16x16x32_f16(a,b,c,0,0,0)
#define BF(W,g,c) (*(const f16x8*)((W) + (((g)*16+(c))*64 + l)*8))
#define BI0(g,c)  (*(const f16x8*)(wIH0 + (((g)*5+(c))*64 + l)*8))

__global__ void init_kernel(const float* __restrict__ Wp,
                            const float* __restrict__ x, const int* __restrict__ mask) {
  long i0 = (long)blockIdx.x * blockDim.x + threadIdx.x;
  long n  = (long)gridDim.x * blockDim.x;
  for (long i = i0; i < NCL; i += n) g_claim[i] = 0;
  for (long i = i0; i < NCL*2*64; i += n) ((int*)g_wflag)[i] = 0;
  for (long i = i0; i < NCL*4*BCL*NH; i += n) { g_h1[i]=(_Float16)0.f; g_h2[i]=(_Float16)0.f; }
  for (long i = i0; i < 2*STPL; i += n) ((float*)g_stats)[i] = 0.f;
  for (long i = i0; i < NH*(NH/2); i += n) g_Wt[i] = Wp[(i & 255)*NH + (i >> 8)];
  const long total = (long)NB*NT*XMS;
  for (long i = i0; i < total + 256; i += n) {
    if (i >= total) { g_xm[i] = (_Float16)0.f; continue; }
    long row = i / XMS; int col = (int)(i % XMS);
    float v = 0.f;
    if (col < NF)          v = x[row*NF + col];
    else if (col < 2*NF)   v = (float)mask[row*NF + col - NF];
    g_xm[i] = (_Float16)v;
  }
}

// Skewed layer-specialized superstep GRU (r14 schedule) with a PER-WAVE
// asymmetric epoch barrier (no __syncthreads, no RMW counter):
//   each wave: [compute+stores] -> vmcnt(0) drain -> store own epoch flag ->
//   cross-barrier prefetches -> poll flags.
// Thresholds to enter s+1: lay0 needs F0>=s+1, F1>=s (one epoch relaxed:
// its h1-slot overwrite only conflicts with lay1's tail-of-(s-2) prefetch,
// whose completion is implied by F1>=s). lay1 needs F0>=s+1, F1>=s+1.
__global__ __launch_bounds__(256, 1) void gru_main(
    const float* __restrict__ Wih0, const float* __restrict__ Whh0,
    const float* __restrict__ bih0, const float* __restrict__ bhh0,
    const float* __restrict__ Wih1, const float* __restrict__ Whh1,
    const float* __restrict__ bih1, const float* __restrict__ bhh1,
    const float* __restrict__ lng,  const float* __restrict__ lnb) {
  extern __shared__ char lds[];
  _Float16* wHH0 = (_Float16*)lds;              // 48KB
  _Float16* wIH1 = (_Float16*)(lds + 49152);    // 48KB
  _Float16* wHH1 = (_Float16*)(lds + 98304);    // 48KB
  _Float16* wIH0 = (_Float16*)(lds + 147456);   // 15KB

  const int tid = threadIdx.x;
  const int w = tid >> 6, l = tid & 63, l15 = l & 15, lgp = l >> 4;
  const int p = w >> 1, lay = w & 1;

  int* bcast = (int*)lds;
  if (tid == 0) {
    unsigned xcc;
    asm volatile("s_getreg_b32 %0, hwreg(HW_REG_XCC_ID)" : "=s"(xcc));
    int c = (int)(xcc & 7u);
    int qq = __hip_atomic_fetch_add(&g_claim[c], 1, __ATOMIC_RELAXED, __HIP_MEMORY_SCOPE_AGENT);
    bcast[0] = c; bcast[1] = qq & 31;
  }
  __syncthreads();
  const int cl = bcast[0], q = bcast[1];
  const int j0 = q * 16;
  __syncthreads();

  for (int e = tid; e < 3*16*NH; e += 256) {
    int k = e & 511, ru = e >> 9;
    int g = ru >> 4, u = ru & 15;
    int src = (g*NH + j0 + u)*NH + k;
    int dst = ((g*16 + (k>>5))*64 + ((((k>>3)&3)<<4) | u))*8 + (k&7);
    wHH0[dst] = (_Float16)Whh0[src];
    wIH1[dst] = (_Float16)Wih1[src];
    wHH1[dst] = (_Float16)Whh1[src];
  }
  for (int e = tid; e < 3*16*160; e += 256) {
    int k = e % 160, ru = e / 160;
    int g = ru >> 4, u = ru & 15;
    float v = (k < 130) ? Wih0[(g*NH + j0 + u)*130 + k] : 0.f;
    int dst = ((g*5 + (k>>5))*64 + ((((k>>3)&3)<<4) | u))*8 + (k&7);
    wIH0[dst] = (_Float16)v;
  }

  const int ucol = j0 + l15;
  const float cbr = lay ? bih1[ucol]+bhh1[ucol]       : bih0[ucol]+bhh0[ucol];
  const float cbz = lay ? bih1[NH+ucol]+bhh1[NH+ucol] : bih0[NH+ucol]+bhh0[NH+ucol];
  const float bin = lay ? bih1[2*NH+ucol]             : bih0[2*NH+ucol];
  const float bhn = lay ? bhh1[2*NH+ucol]             : bhh0[2*NH+ucol];

  const int arow0 = (p*16 + l15)*NH + lgp*8;          // f16 units within a slot
  const int sOff  = ((cl*BCL + p*16 + l15)*BPC + lgp*8)*2;   // floats, in-plane
  const _Float16* xptr = g_xm + ((long)(cl*BCL + p*16 + l15)*NT)*XMS + lgp*8;

  const i32x4 srdH1 = make_srd(g_h1 + (size_t)cl*4*BCL*NH);
  const i32x4 srdH2 = make_srd(g_h2 + (size_t)cl*4*BCL*NH);
  const i32x4 srdST = make_srd(g_stats);

  float hloc[4] = {0,0,0,0};
  float A1[4]={0,0,0,0}, A0[4]={0,0,0,0}, lastc[4]={0,0,0,0};
  f16x8 af1[16], xmf[5];
  f32x4 sts0, sts1, sts2, sts3;
  const f32x4 z4v = {0.f,0.f,0.f,0.f};

  auto lnFinish = [&](bool last) {   // uses hloc BEFORE the gate-math update
    float s  = (sts0[0]+sts1[0]) + (sts2[0]+sts3[0]) + (sts0[2]+sts1[2]) + (sts2[2]+sts3[2]);
    float ss = (sts0[1]+sts1[1]) + (sts2[1]+sts3[1]) + (sts0[3]+sts1[3]) + (sts2[3]+sts3[3]);
    s += __shfl_xor(s,16); ss += __shfl_xor(ss,16);
    s += __shfl_xor(s,32); ss += __shfl_xor(ss,32);
    #pragma unroll
    for (int r = 0; r < 4; r++) {
      float S = __shfl(s, lgp*4+r), SS = __shfl(ss, lgp*4+r);
      float mu = S*(1.f/NH), var = SS*(1.f/NH) - mu*mu;
      float inv = rsqrtf(var + 1e-5f);
      A1[r] += hloc[r]*inv; A0[r] += mu*inv;
      if (last) lastc[r] = (hloc[r]-mu)*inv;
    }
  };
  // Paired u32 store of this wave's h tile (even lanes store 2 f16 as one
  // dword: no sub-dword RMW; memory layout identical to the f16 array).
  auto stPair = [&](_Float16* hw, int row, float v) {
    unsigned lo = (unsigned)__builtin_bit_cast(unsigned short, (_Float16)v);
    unsigned hi = (unsigned)__shfl_xor((int)lo, 1);
    if (!(l15 & 1))
      st_c((unsigned*)(hw + row*NH + j0 + l15), lo | (hi << 16));
  };

  __syncthreads();   // weight packs visible (last block-wide sync)
  if (lay == 0) {    // xm(0) prefetch (plain loads; immutable data)
    #pragma unroll
    for (int c = 0; c < 5; c++) xmf[c] = *(const f16x8*)(xptr + c*32);
  }

  for (int s = 0; s <= NT+1; ++s) {
    if (lay == 0) {
      if (s < NT) {
        // fresh h1(s-1): the single tight-edge load
        const int vb = 2*(((s+3)&3)*BCL*NH + arow0);
        f16x8 ah[16];
        #pragma unroll
        for (int c = 0; c < 16; c++) ah[c] = bldh(srdH1, vb + c*64);
        f32x4 aR=z4v, aZ=z4v, aNi=z4v, aNh=z4v;
        #pragma unroll
        for (int c = 0; c < 5; c++) {
          aR  = MF(xmf[c], BI0(0,c), aR);
          aZ  = MF(xmf[c], BI0(1,c), aZ);
          aNi = MF(xmf[c], BI0(2,c), aNi);
        }
        #pragma unroll
        for (int c = 0; c < 16; c++) {
          aR  = MF(ah[c], BF(wHH0,0,c), aR);
          aZ  = MF(ah[c], BF(wHH0,1,c), aZ);
          aNh = MF(ah[c], BF(wHH0,2,c), aNh);
        }
        #pragma unroll
        for (int r = 0; r < 4; r++) {
          float rg = sigm(aR[r] + cbr);
          float zg = sigm(aZ[r] + cbz);
          float ng = tanh_(aNi[r] + bin + rg*(aNh[r] + bhn));
          hloc[r] = (1.f-zg)*ng + zg*hloc[r];
        }
        _Float16* hw = g_h1 + (size_t)(cl*4 + (s&3))*BCL*NH;
        #pragma unroll
        for (int r = 0; r < 4; r++) stPair(hw, p*16 + lgp*4 + r, hloc[r]);
      }
    } else {   // lay1: computes h2(s-2)
      if (s >= 2) {
        // h2(s-3) + stats(s-3): published 1 epoch ago; h1(s-2) prefetched
        const int vb2 = 2*(((s+1)&3)*BCL*NH + arow0);
        f16x8 ag2[16];
        #pragma unroll
        for (int c = 0; c < 16; c++) ag2[c] = bldh(srdH2, vb2 + c*64);
        const int vbs = 4*(((s+1)&1)*STPL + sOff);
        sts0 = __builtin_bit_cast(f32x4, bld(srdST, vbs));
        sts1 = __builtin_bit_cast(f32x4, bld(srdST, vbs + 16));
        sts2 = __builtin_bit_cast(f32x4, bld(srdST, vbs + 32));
        sts3 = __builtin_bit_cast(f32x4, bld(srdST, vbs + 48));
        f32x4 aR=z4v, aZ=z4v, aNi=z4v, aNh=z4v;
        #pragma unroll
        for (int c = 0; c < 16; c++) {   // ih1 first: af1 already resident
          aR  = MF(af1[c], BF(wIH1,0,c), aR);
          aZ  = MF(af1[c], BF(wIH1,1,c), aZ);
          aNi = MF(af1[c], BF(wIH1,2,c), aNi);
        }
        #pragma unroll
        for (int c = 0; c < 16; c++) {   // hh1: waits ag2 (hidden under ih1)
          aR  = MF(ag2[c], BF(wHH1,0,c), aR);
          aZ  = MF(ag2[c], BF(wHH1,1,c), aZ);
          aNh = MF(ag2[c], BF(wHH1,2,c), aNh);
        }
        if (s >= 3) lnFinish(false);   // t=s-3, hloc still h2(s-3)
        _Float16* hw = g_h2 + (size_t)(cl*4 + ((s+2)&3))*BCL*NH;
        float* swb = g_stats[s&1];
        #pragma unroll
        for (int r = 0; r < 4; r++) {
          int row = p*16 + lgp*4 + r;
          float rg = sigm(aR[r] + cbr);
          float zg = sigm(aZ[r] + cbz);
          float ng = tanh_(aNi[r] + bin + rg*(aNh[r] + bhn));
          hloc[r] = (1.f-zg)*ng + zg*hloc[r];
          stPair(hw, row, hloc[r]);
          float v = hloc[r], v2 = hloc[r]*hloc[r];
          v += __shfl_xor(v,1); v2 += __shfl_xor(v2,1);
          v += __shfl_xor(v,2); v2 += __shfl_xor(v2,2);
          v += __shfl_xor(v,4); v2 += __shfl_xor(v2,4);
          v += __shfl_xor(v,8); v2 += __shfl_xor(v2,8);
          if (l15 == 0) {
            unsigned long long sv =
                (unsigned long long)__builtin_bit_cast(unsigned, v)
              | ((unsigned long long)__builtin_bit_cast(unsigned, v2) << 32);
            st_c64((unsigned long long*)(swb + ((cl*BCL + row)*BPC + q)*2), sv);
          }
        }
      }
    }

    // ---- per-wave epoch barrier ----
    asm volatile("s_waitcnt vmcnt(0)" ::: "memory");   // drain own agent stores
    __builtin_amdgcn_sched_barrier(0);
    st_fl(&g_wflag[cl][lay][q*2 + p], s + 1);
    // cross-barrier prefetches (data published >= 1 epoch ago; intrinsic
    // loads are spill-safe — the waitcnt pass guards every use)
    if (lay == 1 && s >= 1 && s <= NT) {   // h1(s-1) for superstep s+1's ih1
      const int vb1 = 2*(((s+3)&3)*BCL*NH + arow0);
      #pragma unroll
      for (int c = 0; c < 16; c++) af1[c] = bldh(srdH1, vb1 + c*64);
    }
    if (lay == 0 && s + 1 < NT) {          // xm(s+1), immutable
      xptr += XMS;
      #pragma unroll
      for (int c = 0; c < 5; c++) xmf[c] = *(const f16x8*)(xptr + c*32);
    }
    {
      const int* f0 = &g_wflag[cl][0][0];
      const int* f1 = &g_wflag[cl][1][0];
      const int t0 = s + 1, t1 = s + lay;  // lay0: F1>=s ; lay1: F1>=s+1
      for (;;) {
        int v0 = ld_fl(f0 + l);
        int v1 = ld_fl(f1 + l);
        if (__all((v0 >= t0) && (v1 >= t1))) break;
        __builtin_amdgcn_s_sleep(1);
      }
    }
  }

  if (lay == 1) {   // final LN for t=NT-1 (stats parity 1) + pooled write
    const int vbs = 4*(1*STPL + sOff);
    sts0 = __builtin_bit_cast(f32x4, bld(srdST, vbs));
    sts1 = __builtin_bit_cast(f32x4, bld(srdST, vbs + 16));
    sts2 = __builtin_bit_cast(f32x4, bld(srdST, vbs + 32));
    sts3 = __builtin_bit_cast(f32x4, bld(srdST, vbs + 48));
    lnFinish(true);
    float gg = lng[ucol], bb = lnb[ucol];
    #pragma unroll
    for (int r = 0; r < 4; r++) {
      float v = gg*(lastc[r] + (A1[r]-A0[r])*(1.f/NT)) + 2.f*bb;
      g_pool[(cl*BCL + p*16 + lgp*4 + r)*NH + ucol] = v;
    }
  }
}

__global__ __launch_bounds__(256) void proj_kernel(const float* __restrict__ bp,
                                                   float* __restrict__ out) {
  __shared__ float pr[NH];
  int b = blockIdx.x, o = threadIdx.x;
  pr[o] = g_pool[b*NH + o];
  pr[o+256] = g_pool[b*NH + 256 + o];
  __syncthreads();
  float acc = bp[o];
  #pragma unroll 8
  for (int u = 0; u < NH; ++u) acc = fmaf(pr[u], g_Wt[u*256 + o], acc);
  out[b*256 + o] = 0.5f*acc*(1.f + erff(acc*0.70710678118654752f));
}

extern "C" void kernel_launch(void* const* d_in, const int* in_sizes, int n_in,
                              void* d_out, int out_size, void* d_ws, size_t ws_size,
                              hipStream_t stream) {
  const float* x    = (const float*)d_in[0];
  const int*   mask = (const int*)d_in[1];
  const float* Wih0 = (const float*)d_in[2];
  const float* Whh0 = (const float*)d_in[3];
  const float* bih0 = (const float*)d_in[4];
  const float* bhh0 = (const float*)d_in[5];
  const float* Wih1 = (const float*)d_in[6];
  const float* Whh1 = (const float*)d_in[7];
  const float* bih1 = (const float*)d_in[8];
  const float* bhh1 = (const float*)d_in[9];
  const float* lng  = (const float*)d_in[10];
  const float* lnb  = (const float*)d_in[11];
  const float* Wp   = (const float*)d_in[12];
  const float* bp   = (const float*)d_in[13];
  float* out = (float*)d_out;
  (void)in_sizes; (void)n_in; (void)out_size; (void)d_ws; (void)ws_size;

  hipFuncSetAttribute(reinterpret_cast<const void*>(gru_main),
                      hipFuncAttributeMaxDynamicSharedMemorySize, 162816);

  hipLaunchKernelGGL(init_kernel, dim3(2048), dim3(256), 0, stream, Wp, x, mask);
  hipLaunchKernelGGL(gru_main, dim3(256), dim3(256), 162816, stream,
                     Wih0, Whh0, bih0, bhh0, Wih1, Whh1, bih1, bhh1, lng, lnb);
  hipLaunchKernelGGL(proj_kernel, dim3(NB), dim3(256), 0, stream, bp, out);
}

// Round 16
// 3667.391 us; speedup vs baseline: 1.7211x; 1.7211x over previous
//
#include <hip/hip_runtime.h>
#include <math.h>

#define NB 256   // batch
#define NT 512   // time steps
#define NF 65    // features
#define NH 512   // hidden
#define NCL 8    // clusters == physical XCDs
#define BPC 32   // blocks per cluster
#define BCL 32   // batch rows per cluster
#define XMS 136  // padded xm row stride (f16)
#define STPL (NCL*BCL*BPC*2)   // stats plane (one parity), floats

typedef __attribute__((ext_vector_type(8))) _Float16 f16x8;
typedef __attribute__((ext_vector_type(4))) float   f32x4;
typedef __attribute__((ext_vector_type(4))) unsigned u32x4;
typedef __attribute__((ext_vector_type(4))) int      i32x4;

// r14 schedule + r7-style flag-line barrier (no RMW, one-line poll).
__device__ __align__(16) int      g_claim[NCL];
__device__ __align__(16) int      g_bflag[NCL][BPC];           // per-block epoch flags
__device__ __align__(16) _Float16 g_h1[NCL*4*BCL*NH];          // [cl][slot][32][512]
__device__ __align__(16) _Float16 g_h2[NCL*4*BCL*NH];
__device__ __align__(16) float    g_stats[2][STPL];            // t-parity
__device__ __align__(16) float    g_pool[NB*NH];
__device__ __align__(16) float    g_Wt[NH*(NH/2)];
__device__ __align__(16) _Float16 g_xm[(size_t)NB*NT*XMS + 256];

__device__ __forceinline__ float sigm(float v)  { return 1.f/(1.f+__expf(-v)); }
__device__ __forceinline__ float tanh_(float v) { return 1.f-2.f/(1.f+__expf(2.f*v)); }

// COMPILER-MODELED coherent load (r12/r14-proven, spill-safe). cpol 17 = SC0|SC1.
__device__ u32x4 llvm_amdgcn_raw_buffer_load_i32x4(i32x4 srsrc, int voffset,
                                                   int soffset, int cpol)
    __asm("llvm.amdgcn.raw.buffer.load.v4i32");
__device__ __forceinline__ u32x4 bld(i32x4 srd, int vo) {
  return llvm_amdgcn_raw_buffer_load_i32x4(srd, vo, 0, 17);
}
__device__ __forceinline__ f16x8 bldh(i32x4 srd, int vo) {
  return __builtin_bit_cast(f16x8, bld(srd, vo));
}
__device__ __forceinline__ i32x4 make_srd(const void* base) {
  union { i32x4 v; unsigned u[4]; } s;
  s.u[0] = (unsigned)(unsigned long long)base;
  s.u[1] = (unsigned)(((unsigned long long)base) >> 32);  // stride = 0
  s.u[2] = 0xFFFFFFFFu;                                   // no bounds check
  s.u[3] = 0x00020000u;                                   // raw dword config
  return s.v;
}

// PROVEN store side (r4-r14): agent-scope relaxed atomic stores.
__device__ __forceinline__ void st_c(unsigned* p, unsigned v) {
  __hip_atomic_store(p, v, __ATOMIC_RELAXED, __HIP_MEMORY_SCOPE_AGENT);
}
__device__ __forceinline__ void st_c64(unsigned long long* p, unsigned long long v) {
  __hip_atomic_store(p, v, __ATOMIC_RELAXED, __HIP_MEMORY_SCOPE_AGENT);
}
__device__ __forceinline__ void st_fl(int* p, int v) {
  __hip_atomic_store(p, v, __ATOMIC_RELAXED, __HIP_MEMORY_SCOPE_AGENT);
}
__device__ __forceinline__ int ld_fl(const int* p) {
  return __hip_atomic_load((int*)p, __ATOMIC_RELAXED, __HIP_MEMORY_SCOPE_AGENT);
}

#define MF(a,b,c) __builtin_amdgcn_mfma_f32_16x16x32_f16(a,b,c,0,0,0)
#define BF(W,g,c) (*(const f16x8*)((W) + (((g)*16+(c))*64 + l)*8))
#define BI0(g,c)  (*(const f16x8*)(wIH0 + (((g)*5+(c))*64 + l)*8))

__global__ void init_kernel(const float* __restrict__ Wp,
                            const float* __restrict__ x, const int* __restrict__ mask) {
  long i0 = (long)blockIdx.x * blockDim.x + threadIdx.x;
  long n  = (long)gridDim.x * blockDim.x;
  for (long i = i0; i < NCL; i += n) g_claim[i] = 0;
  for (long i = i0; i < NCL*BPC; i += n) ((int*)g_bflag)[i] = 0;
  for (long i = i0; i < NCL*4*BCL*NH; i += n) { g_h1[i]=(_Float16)0.f; g_h2[i]=(_Float16)0.f; }
  for (long i = i0; i < 2*STPL; i += n) ((float*)g_stats)[i] = 0.f;
  for (long i = i0; i < NH*(NH/2); i += n) g_Wt[i] = Wp[(i & 255)*NH + (i >> 8)];
  const long total = (long)NB*NT*XMS;
  for (long i = i0; i < total + 256; i += n) {
    if (i >= total) { g_xm[i] = (_Float16)0.f; continue; }
    long row = i / XMS; int col = (int)(i % XMS);
    float v = 0.f;
    if (col < NF)          v = x[row*NF + col];
    else if (col < 2*NF)   v = (float)mask[row*NF + col - NF];
    g_xm[i] = (_Float16)v;
  }
}

// Skewed layer-specialized superstep GRU (r14 schedule, 3.77ms-proven):
// superstep s: lay0 (w0,w2) computes h1(s) [only tight edge: h1(s-1)];
// lay1 (w1,w3) computes h2(s-2) [h1(s-2): prefetched across the barrier;
// h2(s-3), stats(s-3): 1 epoch old, loaded at top].
// Barrier (r7 shape, replaces r14's RMW counter): drain-syncthreads ->
// tid0 plain flag store (32 addrs in ONE line; no RMW serialization) ->
// prefetch issue -> w0 polls the 32-flag line (one coalesced read/iter) ->
// release syncthreads.
__global__ __launch_bounds__(256, 1) void gru_main(
    const float* __restrict__ Wih0, const float* __restrict__ Whh0,
    const float* __restrict__ bih0, const float* __restrict__ bhh0,
    const float* __restrict__ Wih1, const float* __restrict__ Whh1,
    const float* __restrict__ bih1, const float* __restrict__ bhh1,
    const float* __restrict__ lng,  const float* __restrict__ lnb) {
  extern __shared__ char lds[];
  _Float16* wHH0 = (_Float16*)lds;              // 48KB
  _Float16* wIH1 = (_Float16*)(lds + 49152);    // 48KB
  _Float16* wHH1 = (_Float16*)(lds + 98304);    // 48KB
  _Float16* wIH0 = (_Float16*)(lds + 147456);   // 15KB

  const int tid = threadIdx.x;
  const int w = tid >> 6, l = tid & 63, l15 = l & 15, lgp = l >> 4;
  const int p = w >> 1, lay = w & 1;

  int* bcast = (int*)lds;
  if (tid == 0) {
    unsigned xcc;
    asm volatile("s_getreg_b32 %0, hwreg(HW_REG_XCC_ID)" : "=s"(xcc));
    int c = (int)(xcc & 7u);
    int qq = __hip_atomic_fetch_add(&g_claim[c], 1, __ATOMIC_RELAXED, __HIP_MEMORY_SCOPE_AGENT);
    bcast[0] = c; bcast[1] = qq & 31;
  }
  __syncthreads();
  const int cl = bcast[0], q = bcast[1];
  const int j0 = q * 16;
  __syncthreads();

  for (int e = tid; e < 3*16*NH; e += 256) {
    int k = e & 511, ru = e >> 9;
    int g = ru >> 4, u = ru & 15;
    int src = (g*NH + j0 + u)*NH + k;
    int dst = ((g*16 + (k>>5))*64 + ((((k>>3)&3)<<4) | u))*8 + (k&7);
    wHH0[dst] = (_Float16)Whh0[src];
    wIH1[dst] = (_Float16)Wih1[src];
    wHH1[dst] = (_Float16)Whh1[src];
  }
  for (int e = tid; e < 3*16*160; e += 256) {
    int k = e % 160, ru = e / 160;
    int g = ru >> 4, u = ru & 15;
    float v = (k < 130) ? Wih0[(g*NH + j0 + u)*130 + k] : 0.f;
    int dst = ((g*5 + (k>>5))*64 + ((((k>>3)&3)<<4) | u))*8 + (k&7);
    wIH0[dst] = (_Float16)v;
  }

  const int ucol = j0 + l15;
  const float cbr = lay ? bih1[ucol]+bhh1[ucol]       : bih0[ucol]+bhh0[ucol];
  const float cbz = lay ? bih1[NH+ucol]+bhh1[NH+ucol] : bih0[NH+ucol]+bhh0[NH+ucol];
  const float bin = lay ? bih1[2*NH+ucol]             : bih0[2*NH+ucol];
  const float bhn = lay ? bhh1[2*NH+ucol]             : bhh0[2*NH+ucol];

  const int arow0 = (p*16 + l15)*NH + lgp*8;          // f16 units within a slot
  const int sOff  = ((cl*BCL + p*16 + l15)*BPC + lgp*8)*2;   // floats, in-plane
  const _Float16* xptr = g_xm + ((long)(cl*BCL + p*16 + l15)*NT)*XMS + lgp*8;

  const i32x4 srdH1 = make_srd(g_h1 + (size_t)cl*4*BCL*NH);
  const i32x4 srdH2 = make_srd(g_h2 + (size_t)cl*4*BCL*NH);
  const i32x4 srdST = make_srd(g_stats);

  float hloc[4] = {0,0,0,0};
  float A1[4]={0,0,0,0}, A0[4]={0,0,0,0}, lastc[4]={0,0,0,0};
  f16x8 af1[16], xmf[5];
  f32x4 sts0, sts1, sts2, sts3;
  const f32x4 z4v = {0.f,0.f,0.f,0.f};

  auto lnFinish = [&](bool last) {   // uses hloc BEFORE the gate-math update
    float s  = (sts0[0]+sts1[0]) + (sts2[0]+sts3[0]) + (sts0[2]+sts1[2]) + (sts2[2]+sts3[2]);
    float ss = (sts0[1]+sts1[1]) + (sts2[1]+sts3[1]) + (sts0[3]+sts1[3]) + (sts2[3]+sts3[3]);
    s += __shfl_xor(s,16); ss += __shfl_xor(ss,16);
    s += __shfl_xor(s,32); ss += __shfl_xor(ss,32);
    #pragma unroll
    for (int r = 0; r < 4; r++) {
      float S = __shfl(s, lgp*4+r), SS = __shfl(ss, lgp*4+r);
      float mu = S*(1.f/NH), var = SS*(1.f/NH) - mu*mu;
      float inv = rsqrtf(var + 1e-5f);
      A1[r] += hloc[r]*inv; A0[r] += mu*inv;
      if (last) lastc[r] = (hloc[r]-mu)*inv;
    }
  };
  // Paired u32 store of this wave's h tile (even lanes store 2 f16 as one
  // dword: no sub-dword RMW; memory layout identical to the f16 array).
  auto stPair = [&](_Float16* hw, int row, float v) {
    unsigned lo = (unsigned)__builtin_bit_cast(unsigned short, (_Float16)v);
    unsigned hi = (unsigned)__shfl_xor((int)lo, 1);
    if (!(l15 & 1))
      st_c((unsigned*)(hw + row*NH + j0 + l15), lo | (hi << 16));
  };

  __syncthreads();   // weight packs visible
  if (lay == 0) {    // xm(0) prefetch (plain loads; immutable data)
    #pragma unroll
    for (int c = 0; c < 5; c++) xmf[c] = *(const f16x8*)(xptr + c*32);
  }

  for (int s = 0; s <= NT+1; ++s) {
    if (lay == 0) {
      if (s < NT) {
        // fresh h1(s-1): the single tight-edge load
        const int vb = 2*(((s+3)&3)*BCL*NH + arow0);
        f16x8 ah[16];
        #pragma unroll
        for (int c = 0; c < 16; c++) ah[c] = bldh(srdH1, vb + c*64);
        f32x4 aR=z4v, aZ=z4v, aNi=z4v, aNh=z4v;
        #pragma unroll
        for (int c = 0; c < 5; c++) {
          aR  = MF(xmf[c], BI0(0,c), aR);
          aZ  = MF(xmf[c], BI0(1,c), aZ);
          aNi = MF(xmf[c], BI0(2,c), aNi);
        }
        #pragma unroll
        for (int c = 0; c < 16; c++) {
          aR  = MF(ah[c], BF(wHH0,0,c), aR);
          aZ  = MF(ah[c], BF(wHH0,1,c), aZ);
          aNh = MF(ah[c], BF(wHH0,2,c), aNh);
        }
        #pragma unroll
        for (int r = 0; r < 4; r++) {
          float rg = sigm(aR[r] + cbr);
          float zg = sigm(aZ[r] + cbz);
          float ng = tanh_(aNi[r] + bin + rg*(aNh[r] + bhn));
          hloc[r] = (1.f-zg)*ng + zg*hloc[r];
        }
        _Float16* hw = g_h1 + (size_t)(cl*4 + (s&3))*BCL*NH;
        #pragma unroll
        for (int r = 0; r < 4; r++) stPair(hw, p*16 + lgp*4 + r, hloc[r]);
      }
    } else {   // lay1: computes h2(s-2)
      if (s >= 2) {
        // h2(s-3) + stats(s-3): published 1 epoch ago; h1(s-2) prefetched
        const int vb2 = 2*(((s+1)&3)*BCL*NH + arow0);
        f16x8 ag2[16];
        #pragma unroll
        for (int c = 0; c < 16; c++) ag2[c] = bldh(srdH2, vb2 + c*64);
        const int vbs = 4*(((s+1)&1)*STPL + sOff);
        sts0 = __builtin_bit_cast(f32x4, bld(srdST, vbs));
        sts1 = __builtin_bit_cast(f32x4, bld(srdST, vbs + 16));
        sts2 = __builtin_bit_cast(f32x4, bld(srdST, vbs + 32));
        sts3 = __builtin_bit_cast(f32x4, bld(srdST, vbs + 48));
        f32x4 aR=z4v, aZ=z4v, aNi=z4v, aNh=z4v;
        #pragma unroll
        for (int c = 0; c < 16; c++) {   // ih1 first: af1 already resident
          aR  = MF(af1[c], BF(wIH1,0,c), aR);
          aZ  = MF(af1[c], BF(wIH1,1,c), aZ);
          aNi = MF(af1[c], BF(wIH1,2,c), aNi);
        }
        #pragma unroll
        for (int c = 0; c < 16; c++) {   // hh1: waits ag2 (hidden under ih1)
          aR  = MF(ag2[c], BF(wHH1,0,c), aR);
          aZ  = MF(ag2[c], BF(wHH1,1,c), aZ);
          aNh = MF(ag2[c], BF(wHH1,2,c), aNh);
        }
        if (s >= 3) lnFinish(false);   // t=s-3, hloc still h2(s-3)
        _Float16* hw = g_h2 + (size_t)(cl*4 + ((s+2)&3))*BCL*NH;
        float* swb = g_stats[s&1];
        #pragma unroll
        for (int r = 0; r < 4; r++) {
          int row = p*16 + lgp*4 + r;
          float rg = sigm(aR[r] + cbr);
          float zg = sigm(aZ[r] + cbz);
          float ng = tanh_(aNi[r] + bin + rg*(aNh[r] + bhn));
          hloc[r] = (1.f-zg)*ng + zg*hloc[r];
          stPair(hw, row, hloc[r]);
          float v = hloc[r], v2 = hloc[r]*hloc[r];
          v += __shfl_xor(v,1); v2 += __shfl_xor(v2,1);
          v += __shfl_xor(v,2); v2 += __shfl_xor(v2,2);
          v += __shfl_xor(v,4); v2 += __shfl_xor(v2,4);
          v += __shfl_xor(v,8); v2 += __shfl_xor(v2,8);
          if (l15 == 0) {
            unsigned long long sv =
                (unsigned long long)__builtin_bit_cast(unsigned, v)
              | ((unsigned long long)__builtin_bit_cast(unsigned, v2) << 32);
            st_c64((unsigned long long*)(swb + ((cl*BCL + row)*BPC + q)*2), sv);
          }
        }
      }
    }

    __syncthreads();   // drains every wave's agent stores (vmcnt0 at barrier)
    if (tid == 0)
      st_fl(&g_bflag[cl][q], s + 1);   // plain store: no RMW serialization
    // cross-barrier prefetches (data published >= 1 epoch ago; intrinsic
    // loads are spill-safe — the waitcnt pass guards every use)
    if (lay == 1 && s >= 1 && s <= NT) {   // h1(s-1) for superstep s+1's ih1
      const int vb1 = 2*(((s+3)&3)*BCL*NH + arow0);
      #pragma unroll
      for (int c = 0; c < 16; c++) af1[c] = bldh(srdH1, vb1 + c*64);
    }
    if (lay == 0 && s + 1 < NT) {          // xm(s+1), immutable
      xptr += XMS;
      #pragma unroll
      for (int c = 0; c < 5; c++) xmf[c] = *(const f16x8*)(xptr + c*32);
    }
    if (w == 0) {                          // one wave polls one flag line
      const int* fp = &g_bflag[cl][0];
      for (;;) {
        int v = (l < BPC) ? ld_fl(fp + l) : (s + 1);
        if (__all(v >= s + 1)) break;
        __builtin_amdgcn_s_sleep(1);
      }
    }
    __syncthreads();   // release
  }

  if (lay == 1) {   // final LN for t=NT-1 (stats parity 1) + pooled write
    const int vbs = 4*(1*STPL + sOff);
    sts0 = __builtin_bit_cast(f32x4, bld(srdST, vbs));
    sts1 = __builtin_bit_cast(f32x4, bld(srdST, vbs + 16));
    sts2 = __builtin_bit_cast(f32x4, bld(srdST, vbs + 32));
    sts3 = __builtin_bit_cast(f32x4, bld(srdST, vbs + 48));
    lnFinish(true);
    float gg = lng[ucol], bb = lnb[ucol];
    #pragma unroll
    for (int r = 0; r < 4; r++) {
      float v = gg*(lastc[r] + (A1[r]-A0[r])*(1.f/NT)) + 2.f*bb;
      g_pool[(cl*BCL + p*16 + lgp*4 + r)*NH + ucol] = v;
    }
  }
}

__global__ __launch_bounds__(256) void proj_kernel(const float* __restrict__ bp,
                                                   float* __restrict__ out) {
  __shared__ float pr[NH];
  int b = blockIdx.x, o = threadIdx.x;
  pr[o] = g_pool[b*NH + o];
  pr[o+256] = g_pool[b*NH + 256 + o];
  __syncthreads();
  float acc = bp[o];
  #pragma unroll 8
  for (int u = 0; u < NH; ++u) acc = fmaf(pr[u], g_Wt[u*256 + o], acc);
  out[b*256 + o] = 0.5f*acc*(1.f + erff(acc*0.70710678118654752f));
}

extern "C" void kernel_launch(void* const* d_in, const int* in_sizes, int n_in,
                              void* d_out, int out_size, void* d_ws, size_t ws_size,
                              hipStream_t stream) {
  const float* x    = (const float*)d_in[0];
  const int*   mask = (const int*)d_in[1];
  const float* Wih0 = (const float*)d_in[2];
  const float* Whh0 = (const float*)d_in[3];
  const float* bih0 = (const float*)d_in[4];
  const float* bhh0 = (const float*)d_in[5];
  const float* Wih1 = (const float*)d_in[6];
  const float* Whh1 = (const float*)d_in[7];
  const float* bih1 = (const float*)d_in[8];
  const float* bhh1 = (const float*)d_in[9];
  const float* lng  = (const float*)d_in[10];
  const float* lnb  = (const float*)d_in[11];
  const float* Wp   = (const float*)d_in[12];
  const float* bp   = (const float*)d_in[13];
  float* out = (float*)d_out;
  (void)in_sizes; (void)n_in; (void)out_size; (void)d_ws; (void)ws_size;

  hipFuncSetAttribute(reinterpret_cast<const void*>(gru_main),
                      hipFuncAttributeMaxDynamicSharedMemorySize, 162816);

  hipLaunchKernelGGL(init_kernel, dim3(2048), dim3(256), 0, stream, Wp, x, mask);
  hipLaunchKernelGGL(gru_main, dim3(256), dim3(256), 162816, stream,
                     Wih0, Whh0, bih0, bhh0, Wih1, Whh1, bih1, bhh1, lng, lnb);
  hipLaunchKernelGGL(proj_kernel, dim3(NB), dim3(256), 0, stream, bp, out);
}